// Round 4
// baseline (158.976 us; speedup 1.0000x reference)
//
#include <hip/hip_runtime.h>
#include <hip/hip_bf16.h>

namespace {

constexpr int kB = 8, kT = 64, kE = 4, kD = 256, kH = 1024;
constexpr int kTE = kT * kE;                    // 256
constexpr size_t kHidElems = (size_t)kB * kTE * kH;   // 2M floats = 8 MB

__device__ __forceinline__ float gelu_exact(float v) {
  return 0.5f * v * (1.0f + erff(v * 0.70710678118654752f));
}

// ---------------- Kernel A: hid[b][te][h] = gelu(x . fc1 + b1) ----------------
// grid = te(256) * 4 h-chunks, 256 threads; thread owns one h column.
// x reads are wave-uniform -> scalar loads (K$), weights stream as 256 B/wave.
__global__ __launch_bounds__(256, 4)
void ffn1_kernel(const float* __restrict__ x,
                 const float* __restrict__ fc1,
                 const float* __restrict__ b1,
                 float* __restrict__ hid) {
  const int tid = threadIdx.x;
  const int bid = blockIdx.x;
  const int te  = bid >> 2;
  const int c   = bid & 3;
  const int t   = te >> 2;
  const int h   = c * 256 + tid;

  const float* __restrict__ wp = fc1 + (size_t)te * (kD * kH) + h;  // stride kH over d
  const float* __restrict__ xp = x + (size_t)t * kD;                // + b*kT*kD + d

  float acc[kB] = {0.f, 0.f, 0.f, 0.f, 0.f, 0.f, 0.f, 0.f};
#pragma unroll 8
  for (int d = 0; d < kD; ++d) {
    const float wv = wp[(size_t)d * kH];
#pragma unroll
    for (int b = 0; b < kB; ++b) {
      const float xv = xp[(size_t)b * (kT * kD) + d];   // uniform -> s_load
      acc[b] = fmaf(xv, wv, acc[b]);
    }
  }
  const float bias = b1[(size_t)te * kH + h];
#pragma unroll
  for (int b = 0; b < kB; ++b)
    hid[((size_t)b * kTE + te) * kH + h] = gelu_exact(acc[b] + bias);
}

// ---------------- Kernel B: out[b][t][d] += gate * (hid . fc2 + b2) ----------------
// grid = te(256) * 4 h-chunks, 256 threads; thread owns one d.
// hid reads are wave-uniform -> scalar loads; fc2 streams 256 B/wave per h.
__global__ __launch_bounds__(256, 4)
void ffn2_kernel(const float* __restrict__ x,
                 const float* __restrict__ hid,
                 const float* __restrict__ fc2,
                 const float* __restrict__ b2,
                 const float* __restrict__ Wr,
                 const float* __restrict__ br,
                 float* __restrict__ out) {
  __shared__ float gates_s[kB];

  const int tid = threadIdx.x;
  const int bid = blockIdx.x;
  const int te  = bid >> 2;
  const int c   = bid & 3;
  const int t   = te >> 2;

  const int wave = tid >> 6, lane = tid & 63;

  // ---- router gates: wave w computes b = 2w, 2w+1 from global x (L1/L2-hot) ----
  {
    const float* __restrict__ wr = Wr + (size_t)te * kD;
    const float w0 = wr[lane], w1 = wr[lane + 64], w2 = wr[lane + 128], w3 = wr[lane + 192];
#pragma unroll
    for (int bb = 0; bb < 2; ++bb) {
      const int b = wave * 2 + bb;
      const float* __restrict__ xb = x + ((size_t)b * kT + t) * kD;
      float p = xb[lane] * w0 + xb[lane + 64] * w1 +
                xb[lane + 128] * w2 + xb[lane + 192] * w3;
#pragma unroll
      for (int off = 32; off; off >>= 1) p += __shfl_xor(p, off);
      if (lane == 0) {
        const float g = p + br[te];
        gates_s[b] = g > 0.0f ? g : 0.0f;
      }
    }
  }
  __syncthreads();

  // ---- stream fc2 chunk; hid via scalar loads ----
  const int h0 = c * 256;
  const float* __restrict__ wp = fc2 + (size_t)te * (kH * kD) + (size_t)h0 * kD + tid;
  const float* __restrict__ hp = hid + (size_t)te * kH + h0;   // + b*kTE*kH + i

  float acc[kB] = {0.f, 0.f, 0.f, 0.f, 0.f, 0.f, 0.f, 0.f};
#pragma unroll 8
  for (int i = 0; i < 256; ++i) {
    const float wv = wp[(size_t)i * kD];
#pragma unroll
    for (int b = 0; b < kB; ++b) {
      const float hv = hp[(size_t)b * (kTE * kH) + i];  // uniform -> s_load
      acc[b] = fmaf(hv, wv, acc[b]);
    }
  }

  const float b2v = (c == 0) ? b2[(size_t)te * kD + tid] : 0.f;
#pragma unroll
  for (int b = 0; b < kB; ++b)
    atomicAdd(&out[((size_t)b * kT + t) * kD + tid], gates_s[b] * (acc[b] + b2v));

  if (c == 0 && tid == 0) {
    float gs = 0.f;
#pragma unroll
    for (int b = 0; b < kB; ++b) gs += gates_s[b];
    atomicAdd(&out[(size_t)kB * kT * kD], 0.01f * gs * (1.0f / (kB * kT)));
  }
}

// ---------------- Fallback (proven R2 kernel) if ws is too small ----------------
constexpr int kNC = 4;
constexpr int kHc = kH / kNC;

__global__ __launch_bounds__(256, 4)
void moe_ffn_fused(const float* __restrict__ x,
                   const float* __restrict__ fc1,
                   const float* __restrict__ b1,
                   const float* __restrict__ fc2,
                   const float* __restrict__ b2,
                   const float* __restrict__ Wr,
                   const float* __restrict__ br,
                   float* __restrict__ out) {
  __shared__ float xs[kB][kD];
  __shared__ float hid[kB][kHc];
  __shared__ float gates_s[kB];

  const int tid = threadIdx.x;
  const int bid = blockIdx.x;
  const int te  = bid / kNC;
  const int c   = bid % kNC;
  const int t   = te >> 2;
  const int h0  = c * kHc;

#pragma unroll
  for (int b = 0; b < kB; ++b)
    xs[b][tid] = x[((size_t)b * kT + t) * kD + tid];
  __syncthreads();

  const int wave = tid >> 6, lane = tid & 63;
  {
    const float* __restrict__ wr = Wr + (size_t)te * kD;
    const float w0 = wr[lane], w1 = wr[lane + 64], w2 = wr[lane + 128], w3 = wr[lane + 192];
#pragma unroll
    for (int bb = 0; bb < 2; ++bb) {
      const int b = wave + bb * 4;
      float p = xs[b][lane] * w0 + xs[b][lane + 64] * w1 +
                xs[b][lane + 128] * w2 + xs[b][lane + 192] * w3;
#pragma unroll
      for (int off = 32; off; off >>= 1) p += __shfl_xor(p, off);
      if (lane == 0) {
        const float g = p + br[te];
        gates_s[b] = g > 0.0f ? g : 0.0f;
      }
    }
  }

  {
    const float* __restrict__ w = fc1 + (size_t)te * kD * kH + h0 + tid;
    float acc[kB] = {0.f, 0.f, 0.f, 0.f, 0.f, 0.f, 0.f, 0.f};
#pragma unroll 8
    for (int d = 0; d < kD; ++d) {
      const float wv = w[(size_t)d * kH];
#pragma unroll
      for (int b = 0; b < kB; ++b) acc[b] = fmaf(xs[b][d], wv, acc[b]);
    }
    const float bias = b1[(size_t)te * kH + h0 + tid];
#pragma unroll
    for (int b = 0; b < kB; ++b) hid[b][tid] = gelu_exact(acc[b] + bias);
  }
  __syncthreads();

  {
    const float* __restrict__ w = fc2 + (size_t)te * kH * kD + (size_t)h0 * kD + tid;
    float acc[kB] = {0.f, 0.f, 0.f, 0.f, 0.f, 0.f, 0.f, 0.f};
#pragma unroll 8
    for (int i = 0; i < kHc; ++i) {
      const float wv = w[(size_t)i * kD];
#pragma unroll
      for (int b = 0; b < kB; ++b) acc[b] = fmaf(hid[b][i], wv, acc[b]);
    }
    const float bias2 = (c == 0) ? b2[(size_t)te * kD + tid] : 0.f;
#pragma unroll
    for (int b = 0; b < kB; ++b)
      atomicAdd(&out[((size_t)b * kT + t) * kD + tid], gates_s[b] * (acc[b] + bias2));

    if (c == 0 && tid == 0) {
      float gs = 0.f;
#pragma unroll
      for (int b = 0; b < kB; ++b) gs += gates_s[b];
      atomicAdd(&out[(size_t)kB * kT * kD], 0.01f * gs * (1.0f / (kB * kT)));
    }
  }
}

}  // namespace

extern "C" void kernel_launch(void* const* d_in, const int* in_sizes, int n_in,
                              void* d_out, int out_size, void* d_ws, size_t ws_size,
                              hipStream_t stream) {
  const float* x   = (const float*)d_in[0];
  const float* fc1 = (const float*)d_in[1];
  const float* b1  = (const float*)d_in[2];
  const float* fc2 = (const float*)d_in[3];
  const float* b2  = (const float*)d_in[4];
  const float* Wr  = (const float*)d_in[5];
  const float* br  = (const float*)d_in[6];
  float* out = (float*)d_out;

  // Zero the accumulation target every call (graph replays must be
  // deterministic; harness does not re-poison between replays).
  hipMemsetAsync(d_out, 0, (size_t)out_size * sizeof(float), stream);

  if (ws_size >= kHidElems * sizeof(float)) {
    float* hid = (float*)d_ws;
    ffn1_kernel<<<dim3(kTE * 4), dim3(256), 0, stream>>>(x, fc1, b1, hid);
    ffn2_kernel<<<dim3(kTE * 4), dim3(256), 0, stream>>>(x, hid, fc2, b2, Wr, br, out);
  } else {
    moe_ffn_fused<<<dim3(kTE * kNC), dim3(256), 0, stream>>>(x, fc1, b1, fc2, b2, Wr, br, out);
  }
}

// Round 5
// 108.959 us; speedup vs baseline: 1.4591x; 1.4591x over previous
//
#include <hip/hip_runtime.h>
#include <hip/hip_bf16.h>

namespace {

constexpr int kB = 8, kT = 64, kE = 4, kD = 256, kH = 1024;
constexpr int kNC = 8;             // H-chunks per (t,e) -> grid 2048, 8 blocks/CU
constexpr int kHc = kH / kNC;      // 128

__device__ __forceinline__ float gelu_exact(float v) {
  return 0.5f * v * (1.0f + erff(v * 0.70710678118654752f));
}

__global__ __launch_bounds__(256, 8)
void moe_ffn_kernel(const float* __restrict__ x,
                    const float* __restrict__ fc1,
                    const float* __restrict__ b1,
                    const float* __restrict__ fc2,
                    const float* __restrict__ b2,
                    const float* __restrict__ Wr,
                    const float* __restrict__ br,
                    float* __restrict__ out) {
  __shared__ float xs[kB][kD];     // 8 KB
  __shared__ float hid[kB][kHc];   // 4 KB
  __shared__ float gates_s[kB];

  const int tid = threadIdx.x;
  const int bid = blockIdx.x;      // te * kNC + c
  const int te  = bid >> 3;
  const int c   = bid & 7;
  const int t   = te >> 2;
  const int h0  = c * kHc;

  // ---- stage x[b, t, :] into LDS as float4 ----
  {
    const float4* __restrict__ xsrc = reinterpret_cast<const float4*>(x);
    float4* xdst = reinterpret_cast<float4*>(&xs[0][0]);
#pragma unroll
    for (int i = 0; i < 2; ++i) {
      const int f = i * 256 + tid;          // 0..511 float4s
      const int b = f >> 6, d4 = f & 63;
      xdst[f] = xsrc[(size_t)(b * kT + t) * (kD / 4) + d4];
    }
  }
  __syncthreads();

  const int wave = tid >> 6, lane = tid & 63;

  // ---- router gates: wave w computes b = 2w, 2w+1 (one-time, cheap) ----
  {
    const float* __restrict__ wr = Wr + (size_t)te * kD;
    const float w0 = wr[lane], w1 = wr[lane + 64], w2 = wr[lane + 128], w3 = wr[lane + 192];
#pragma unroll
    for (int bb = 0; bb < 2; ++bb) {
      const int b = wave * 2 + bb;
      float p = xs[b][lane] * w0 + xs[b][lane + 64] * w1 +
                xs[b][lane + 128] * w2 + xs[b][lane + 192] * w3;
#pragma unroll
      for (int off = 32; off; off >>= 1) p += __shfl_xor(p, off);
      if (lane == 0) {
        const float g = p + br[te];
        gates_s[b] = g > 0.0f ? g : 0.0f;
      }
    }
  }

  // ---- phase 1: hid[b][hl] = gelu(x . fc1[:, h0+hl] + b1), d split across halves ----
  const int half = tid >> 7;       // waves 0,1 -> d 0..127 ; waves 2,3 -> d 128..255
  const int hl   = tid & 127;
  float acc[kB] = {0.f, 0.f, 0.f, 0.f, 0.f, 0.f, 0.f, 0.f};
  {
    const float* __restrict__ wp = fc1 + (size_t)te * (kD * kH) + h0 + hl;
    const int dbase = half * 128;
#pragma unroll 2
    for (int d4 = 0; d4 < 32; ++d4) {
      const int d = dbase + d4 * 4;
      const float w0 = wp[(size_t)(d + 0) * kH];
      const float w1 = wp[(size_t)(d + 1) * kH];
      const float w2 = wp[(size_t)(d + 2) * kH];
      const float w3 = wp[(size_t)(d + 3) * kH];
      // broadcast b128 reads, 4 b's at a time (bounded live range)
#pragma unroll
      for (int bg = 0; bg < 2; ++bg) {
        float4 xv[4];
#pragma unroll
        for (int j = 0; j < 4; ++j)
          xv[j] = *reinterpret_cast<const float4*>(&xs[bg * 4 + j][d]);
#pragma unroll
        for (int j = 0; j < 4; ++j) {
          const int b = bg * 4 + j;
          acc[b] = fmaf(xv[j].x, w0, acc[b]);
          acc[b] = fmaf(xv[j].y, w1, acc[b]);
          acc[b] = fmaf(xv[j].z, w2, acc[b]);
          acc[b] = fmaf(xv[j].w, w3, acc[b]);
        }
      }
    }
  }
  if (half == 1) {
#pragma unroll
    for (int b = 0; b < kB; ++b) hid[b][hl] = acc[b];
  }
  __syncthreads();
  if (half == 0) {
    const float bias = b1[(size_t)te * kH + h0 + hl];
#pragma unroll
    for (int b = 0; b < kB; ++b)
      hid[b][hl] = gelu_exact(hid[b][hl] + acc[b] + bias);
  }
  __syncthreads();

  // ---- phase 2: thread owns d = tid; sum over chunk's 128 h ----
  {
    const float* __restrict__ wp =
        fc2 + (size_t)te * (kH * kD) + (size_t)h0 * kD + tid;
    float acc2[kB] = {0.f, 0.f, 0.f, 0.f, 0.f, 0.f, 0.f, 0.f};
#pragma unroll 2
    for (int h4 = 0; h4 < 32; ++h4) {
      const float w0 = wp[(size_t)(h4 * 4 + 0) * kD];
      const float w1 = wp[(size_t)(h4 * 4 + 1) * kD];
      const float w2 = wp[(size_t)(h4 * 4 + 2) * kD];
      const float w3 = wp[(size_t)(h4 * 4 + 3) * kD];
#pragma unroll
      for (int bg = 0; bg < 2; ++bg) {
        float4 hv[4];
#pragma unroll
        for (int j = 0; j < 4; ++j)
          hv[j] = *reinterpret_cast<const float4*>(&hid[bg * 4 + j][h4 * 4]);
#pragma unroll
        for (int j = 0; j < 4; ++j) {
          const int b = bg * 4 + j;
          acc2[b] = fmaf(hv[j].x, w0, acc2[b]);
          acc2[b] = fmaf(hv[j].y, w1, acc2[b]);
          acc2[b] = fmaf(hv[j].z, w2, acc2[b]);
          acc2[b] = fmaf(hv[j].w, w3, acc2[b]);
        }
      }
    }
    const float b2v = (c == 0) ? b2[(size_t)te * kD + tid] : 0.f;
#pragma unroll
    for (int b = 0; b < kB; ++b)
      atomicAdd(&out[((size_t)b * kT + t) * kD + tid], gates_s[b] * (acc2[b] + b2v));

    if (c == 0 && tid == 0) {
      float gs = 0.f;
#pragma unroll
      for (int b = 0; b < kB; ++b) gs += gates_s[b];
      atomicAdd(&out[(size_t)kB * kT * kD], 0.01f * gs * (1.0f / (kB * kT)));
    }
  }
}

}  // namespace

extern "C" void kernel_launch(void* const* d_in, const int* in_sizes, int n_in,
                              void* d_out, int out_size, void* d_ws, size_t ws_size,
                              hipStream_t stream) {
  const float* x   = (const float*)d_in[0];
  const float* fc1 = (const float*)d_in[1];
  const float* b1  = (const float*)d_in[2];
  const float* fc2 = (const float*)d_in[3];
  const float* b2  = (const float*)d_in[4];
  const float* Wr  = (const float*)d_in[5];
  const float* br  = (const float*)d_in[6];
  float* out = (float*)d_out;

  // Zero the accumulation target every call (graph replays must be
  // deterministic; harness does not re-poison between replays).
  hipMemsetAsync(d_out, 0, (size_t)out_size * sizeof(float), stream);

  moe_ffn_kernel<<<dim3(kT * kE * kNC), dim3(256), 0, stream>>>(
      x, fc1, b1, fc2, b2, Wr, br, out);
}

// Round 6
// 107.195 us; speedup vs baseline: 1.4831x; 1.0165x over previous
//
#include <hip/hip_runtime.h>
#include <hip/hip_bf16.h>

namespace {

constexpr int kB = 8, kT = 64, kE = 4, kD = 256, kH = 1024;
constexpr int kNC = 4;            // H-chunks per (t,e) -> grid 1024
constexpr int kHc = kH / kNC;     // 256

__device__ __forceinline__ float gelu_exact(float v) {
  return 0.5f * v * (1.0f + erff(v * 0.70710678118654752f));
}

__global__ __launch_bounds__(256, 4)
void moe_ffn_kernel(const float* __restrict__ x,
                    const float* __restrict__ fc1,
                    const float* __restrict__ b1,
                    const float* __restrict__ fc2,
                    const float* __restrict__ b2,
                    const float* __restrict__ Wr,
                    const float* __restrict__ br,
                    float* __restrict__ out) {
  __shared__ float xs[kB][kD];      // 8 KB
  __shared__ float hid[kB][kHc];    // 8 KB
  __shared__ float red[kB][kD];     // 8 KB
  __shared__ float gates_s[kB];

  const int tid  = threadIdx.x;
  const int bid  = blockIdx.x;      // te * kNC + c
  const int te   = bid >> 2;
  const int c    = bid & 3;
  const int t    = te >> 2;
  const int h0   = c * kHc;
  const int wave = tid >> 6, lane = tid & 63;

  // ---- stage x[b, t, :] into LDS as float4 ----
  {
    const float4* __restrict__ xsrc = reinterpret_cast<const float4*>(x);
    float4* xdst = reinterpret_cast<float4*>(&xs[0][0]);
#pragma unroll
    for (int i = 0; i < 2; ++i) {
      const int f = i * 256 + tid;            // 0..511 float4s
      const int b = f >> 6, d4 = f & 63;
      xdst[f] = xsrc[(size_t)(b * kT + t) * (kD / 4) + d4];
    }
  }
  __syncthreads();

  // ---- router gates: wave w computes b = 2w, 2w+1 ----
  {
    const float* __restrict__ wr = Wr + (size_t)te * kD;
    const float w0 = wr[lane], w1 = wr[lane + 64], w2 = wr[lane + 128], w3 = wr[lane + 192];
#pragma unroll
    for (int bb = 0; bb < 2; ++bb) {
      const int b = wave * 2 + bb;
      float p = xs[b][lane] * w0 + xs[b][lane + 64] * w1 +
                xs[b][lane + 128] * w2 + xs[b][lane + 192] * w3;
#pragma unroll
      for (int off = 32; off; off >>= 1) p += __shfl_xor(p, off);
      if (lane == 0) {
        const float g = p + br[te];
        gates_s[b] = g > 0.0f ? g : 0.0f;
      }
    }
  }

  // ---- phase 1: wave owns d-quarter [64*wave, +64); lane owns h = h0+4*lane..+3 ----
  // fc1 loads are dwordx4: wave-instr = 64 lanes * 16 B = 1 KB contiguous.
  float4 acc[kB];
#pragma unroll
  for (int b = 0; b < kB; ++b) acc[b] = make_float4(0.f, 0.f, 0.f, 0.f);
  {
    const float4* __restrict__ wp =
        reinterpret_cast<const float4*>(fc1 + (size_t)te * (kD * kH));  // [d][kH/4]
    const int hq = (h0 >> 2) + lane;
    const int d0 = wave * 64;
    for (int dg = 0; dg < 16; ++dg) {
      const int d = d0 + dg * 4;
      const float4 wv0 = wp[(size_t)(d + 0) * (kH / 4) + hq];
      const float4 wv1 = wp[(size_t)(d + 1) * (kH / 4) + hq];
      const float4 wv2 = wp[(size_t)(d + 2) * (kH / 4) + hq];
      const float4 wv3 = wp[(size_t)(d + 3) * (kH / 4) + hq];
#pragma unroll
      for (int b = 0; b < kB; ++b) {
        const float4 xv = *reinterpret_cast<const float4*>(&xs[b][d]);
        acc[b].x = fmaf(xv.x, wv0.x, acc[b].x);
        acc[b].y = fmaf(xv.x, wv0.y, acc[b].y);
        acc[b].z = fmaf(xv.x, wv0.z, acc[b].z);
        acc[b].w = fmaf(xv.x, wv0.w, acc[b].w);
        acc[b].x = fmaf(xv.y, wv1.x, acc[b].x);
        acc[b].y = fmaf(xv.y, wv1.y, acc[b].y);
        acc[b].z = fmaf(xv.y, wv1.z, acc[b].z);
        acc[b].w = fmaf(xv.y, wv1.w, acc[b].w);
        acc[b].x = fmaf(xv.z, wv2.x, acc[b].x);
        acc[b].y = fmaf(xv.z, wv2.y, acc[b].y);
        acc[b].z = fmaf(xv.z, wv2.z, acc[b].z);
        acc[b].w = fmaf(xv.z, wv2.w, acc[b].w);
        acc[b].x = fmaf(xv.w, wv3.x, acc[b].x);
        acc[b].y = fmaf(xv.w, wv3.y, acc[b].y);
        acc[b].z = fmaf(xv.w, wv3.z, acc[b].z);
        acc[b].w = fmaf(xv.w, wv3.w, acc[b].w);
      }
    }
  }
  // cross-wave combine into hid by rotation (sequential b128, conflict-free)
#pragma unroll
  for (int g = 0; g < 4; ++g) {
    if (wave == g) {
#pragma unroll
      for (int b = 0; b < kB; ++b) {
        float4* hp = reinterpret_cast<float4*>(&hid[b][0]) + lane;
        if (g == 0) {
          *hp = acc[b];
        } else {
          float4 v = *hp;
          v.x += acc[b].x; v.y += acc[b].y; v.z += acc[b].z; v.w += acc[b].w;
          *hp = v;
        }
      }
    }
    __syncthreads();
  }
  // bias + gelu pass: thread owns column tid
  {
    const float bias = b1[(size_t)te * kH + h0 + tid];
#pragma unroll
    for (int b = 0; b < kB; ++b) hid[b][tid] = gelu_exact(hid[b][tid] + bias);
  }
  __syncthreads();

  // ---- phase 2: lane owns d = 4*lane..+3; wave owns h-strip [h0+64*wave, +64) ----
  // fc2 loads are dwordx4 and the strip is 64 consecutive 1 KB rows -> pure stream.
  float4 acc2[kB];
#pragma unroll
  for (int b = 0; b < kB; ++b) acc2[b] = make_float4(0.f, 0.f, 0.f, 0.f);
  {
    const float4* __restrict__ wp =
        reinterpret_cast<const float4*>(fc2 + (size_t)te * (kH * kD));  // [h][kD/4]
    const int hb = wave * 64;
    for (int hg = 0; hg < 16; ++hg) {
      const int hl = hb + hg * 4;
      const int h  = h0 + hl;
      const float4 wv0 = wp[(size_t)(h + 0) * (kD / 4) + lane];
      const float4 wv1 = wp[(size_t)(h + 1) * (kD / 4) + lane];
      const float4 wv2 = wp[(size_t)(h + 2) * (kD / 4) + lane];
      const float4 wv3 = wp[(size_t)(h + 3) * (kD / 4) + lane];
#pragma unroll
      for (int b = 0; b < kB; ++b) {
        const float4 hv = *reinterpret_cast<const float4*>(&hid[b][hl]);
        acc2[b].x = fmaf(hv.x, wv0.x, acc2[b].x);
        acc2[b].y = fmaf(hv.x, wv0.y, acc2[b].y);
        acc2[b].z = fmaf(hv.x, wv0.z, acc2[b].z);
        acc2[b].w = fmaf(hv.x, wv0.w, acc2[b].w);
        acc2[b].x = fmaf(hv.y, wv1.x, acc2[b].x);
        acc2[b].y = fmaf(hv.y, wv1.y, acc2[b].y);
        acc2[b].z = fmaf(hv.y, wv1.z, acc2[b].z);
        acc2[b].w = fmaf(hv.y, wv1.w, acc2[b].w);
        acc2[b].x = fmaf(hv.z, wv2.x, acc2[b].x);
        acc2[b].y = fmaf(hv.z, wv2.y, acc2[b].y);
        acc2[b].z = fmaf(hv.z, wv2.z, acc2[b].z);
        acc2[b].w = fmaf(hv.z, wv2.w, acc2[b].w);
        acc2[b].x = fmaf(hv.w, wv3.x, acc2[b].x);
        acc2[b].y = fmaf(hv.w, wv3.y, acc2[b].y);
        acc2[b].z = fmaf(hv.w, wv3.z, acc2[b].z);
        acc2[b].w = fmaf(hv.w, wv3.w, acc2[b].w);
      }
    }
  }
  // cross-wave combine into red by rotation
#pragma unroll
  for (int g = 0; g < 4; ++g) {
    if (wave == g) {
#pragma unroll
      for (int b = 0; b < kB; ++b) {
        float4* rp = reinterpret_cast<float4*>(&red[b][0]) + lane;
        if (g == 0) {
          *rp = acc2[b];
        } else {
          float4 v = *rp;
          v.x += acc2[b].x; v.y += acc2[b].y; v.z += acc2[b].z; v.w += acc2[b].w;
          *rp = v;
        }
      }
    }
    __syncthreads();
  }

  // ---- epilogue: thread owns d = tid; gate-scale and accumulate over e ----
  {
    const float b2v = (c == 0) ? b2[(size_t)te * kD + tid] : 0.f;
#pragma unroll
    for (int b = 0; b < kB; ++b)
      atomicAdd(&out[((size_t)b * kT + t) * kD + tid], gates_s[b] * (red[b][tid] + b2v));

    if (c == 0 && tid == 0) {
      float gs = 0.f;
#pragma unroll
      for (int b = 0; b < kB; ++b) gs += gates_s[b];
      atomicAdd(&out[(size_t)kB * kT * kD], 0.01f * gs * (1.0f / (kB * kT)));
    }
  }
}

}  // namespace

extern "C" void kernel_launch(void* const* d_in, const int* in_sizes, int n_in,
                              void* d_out, int out_size, void* d_ws, size_t ws_size,
                              hipStream_t stream) {
  const float* x   = (const float*)d_in[0];
  const float* fc1 = (const float*)d_in[1];
  const float* b1  = (const float*)d_in[2];
  const float* fc2 = (const float*)d_in[3];
  const float* b2  = (const float*)d_in[4];
  const float* Wr  = (const float*)d_in[5];
  const float* br  = (const float*)d_in[6];
  float* out = (float*)d_out;

  // Zero the accumulation target every call (graph replays must be
  // deterministic; harness does not re-poison between replays).
  hipMemsetAsync(d_out, 0, (size_t)out_size * sizeof(float), stream);

  moe_ffn_kernel<<<dim3(kT * kE * kNC), dim3(256), 0, stream>>>(
      x, fc1, b1, fc2, b2, Wr, br, out);
}

// Round 8
// 95.318 us; speedup vs baseline: 1.6678x; 1.1246x over previous
//
#include <hip/hip_runtime.h>
#include <hip/hip_bf16.h>

namespace {

constexpr int kB = 8, kT = 64, kE = 4, kD = 256, kH = 1024;
constexpr int kNC = 4;            // H-chunks per (t,e) -> grid 1024
constexpr int kHc = kH / kNC;     // 256

typedef float floatx4 __attribute__((ext_vector_type(4)));

__device__ __forceinline__ float gelu_exact(float v) {
  return 0.5f * v * (1.0f + erff(v * 0.70710678118654752f));
}

__device__ __forceinline__ float4 ntload4(const float4* p) {
  const floatx4 v = __builtin_nontemporal_load(reinterpret_cast<const floatx4*>(p));
  return make_float4(v.x, v.y, v.z, v.w);
}

__global__ __launch_bounds__(256, 4)
void moe_ffn_kernel(const float* __restrict__ x,
                    const float* __restrict__ fc1,
                    const float* __restrict__ b1,
                    const float* __restrict__ fc2,
                    const float* __restrict__ b2,
                    const float* __restrict__ Wr,
                    const float* __restrict__ br,
                    float* __restrict__ out) {
  __shared__ float xs[kB][kD];      // 8 KB
  __shared__ float hid[kB][kHc];    // 8 KB
  __shared__ float red[kB][kD];     // 8 KB
  __shared__ float gates_s[kB];

  const int tid  = threadIdx.x;
  const int bid  = blockIdx.x;      // te * kNC + c
  const int te   = bid >> 2;
  const int c    = bid & 3;
  const int t    = te >> 2;
  const int h0   = c * kHc;
  const int wave = tid >> 6, lane = tid & 63;

  // ---- stage x[b, t, :] into LDS as float4 (cached loads) ----
  {
    const float4* __restrict__ xsrc = reinterpret_cast<const float4*>(x);
    float4* xdst = reinterpret_cast<float4*>(&xs[0][0]);
#pragma unroll
    for (int i = 0; i < 2; ++i) {
      const int f = i * 256 + tid;            // 0..511 float4s
      const int b = f >> 6, d4 = f & 63;
      xdst[f] = xsrc[(size_t)(b * kT + t) * (kD / 4) + d4];
    }
  }
  __syncthreads();

  // ---- router gates: wave w computes b = 2w, 2w+1 ----
  {
    const float* __restrict__ wr = Wr + (size_t)te * kD;
    const float w0 = wr[lane], w1 = wr[lane + 64], w2 = wr[lane + 128], w3 = wr[lane + 192];
#pragma unroll
    for (int bb = 0; bb < 2; ++bb) {
      const int b = wave * 2 + bb;
      float p = xs[b][lane] * w0 + xs[b][lane + 64] * w1 +
                xs[b][lane + 128] * w2 + xs[b][lane + 192] * w3;
#pragma unroll
      for (int off = 32; off; off >>= 1) p += __shfl_xor(p, off);
      if (lane == 0) {
        const float g = p + br[te];
        gates_s[b] = g > 0.0f ? g : 0.0f;
      }
    }
  }

  // ---- phase 1: wave owns d-quarter [64*wave, +64); lane owns h = h0+4*lane..+3 ----
  // fc1 loads: non-temporal dwordx4 (no L2/L3 allocation).
  float4 acc[kB];
#pragma unroll
  for (int b = 0; b < kB; ++b) acc[b] = make_float4(0.f, 0.f, 0.f, 0.f);
  {
    const float4* __restrict__ wp =
        reinterpret_cast<const float4*>(fc1 + (size_t)te * (kD * kH));  // [d][kH/4]
    const int hq = (h0 >> 2) + lane;
    const int d0 = wave * 64;
    for (int dg = 0; dg < 16; ++dg) {
      const int d = d0 + dg * 4;
      const float4 wv0 = ntload4(wp + (size_t)(d + 0) * (kH / 4) + hq);
      const float4 wv1 = ntload4(wp + (size_t)(d + 1) * (kH / 4) + hq);
      const float4 wv2 = ntload4(wp + (size_t)(d + 2) * (kH / 4) + hq);
      const float4 wv3 = ntload4(wp + (size_t)(d + 3) * (kH / 4) + hq);
#pragma unroll
      for (int b = 0; b < kB; ++b) {
        const float4 xv = *reinterpret_cast<const float4*>(&xs[b][d]);
        acc[b].x = fmaf(xv.x, wv0.x, acc[b].x);
        acc[b].y = fmaf(xv.x, wv0.y, acc[b].y);
        acc[b].z = fmaf(xv.x, wv0.z, acc[b].z);
        acc[b].w = fmaf(xv.x, wv0.w, acc[b].w);
        acc[b].x = fmaf(xv.y, wv1.x, acc[b].x);
        acc[b].y = fmaf(xv.y, wv1.y, acc[b].y);
        acc[b].z = fmaf(xv.y, wv1.z, acc[b].z);
        acc[b].w = fmaf(xv.y, wv1.w, acc[b].w);
        acc[b].x = fmaf(xv.z, wv2.x, acc[b].x);
        acc[b].y = fmaf(xv.z, wv2.y, acc[b].y);
        acc[b].z = fmaf(xv.z, wv2.z, acc[b].z);
        acc[b].w = fmaf(xv.z, wv2.w, acc[b].w);
        acc[b].x = fmaf(xv.w, wv3.x, acc[b].x);
        acc[b].y = fmaf(xv.w, wv3.y, acc[b].y);
        acc[b].z = fmaf(xv.w, wv3.z, acc[b].z);
        acc[b].w = fmaf(xv.w, wv3.w, acc[b].w);
      }
    }
  }
  // cross-wave combine into hid by rotation (sequential b128, conflict-free)
#pragma unroll
  for (int g = 0; g < 4; ++g) {
    if (wave == g) {
#pragma unroll
      for (int b = 0; b < kB; ++b) {
        float4* hp = reinterpret_cast<float4*>(&hid[b][0]) + lane;
        if (g == 0) {
          *hp = acc[b];
        } else {
          float4 v = *hp;
          v.x += acc[b].x; v.y += acc[b].y; v.z += acc[b].z; v.w += acc[b].w;
          *hp = v;
        }
      }
    }
    __syncthreads();
  }
  // bias + gelu pass: thread owns column tid
  {
    const float bias = b1[(size_t)te * kH + h0 + tid];
#pragma unroll
    for (int b = 0; b < kB; ++b) hid[b][tid] = gelu_exact(hid[b][tid] + bias);
  }
  __syncthreads();

  // ---- phase 2: lane owns d = 4*lane..+3; wave owns h-strip [h0+64*wave, +64) ----
  // fc2 loads: non-temporal dwordx4, 64 consecutive 1 KB rows per wave.
  float4 acc2[kB];
#pragma unroll
  for (int b = 0; b < kB; ++b) acc2[b] = make_float4(0.f, 0.f, 0.f, 0.f);
  {
    const float4* __restrict__ wp =
        reinterpret_cast<const float4*>(fc2 + (size_t)te * (kH * kD));  // [h][kD/4]
    const int hb = wave * 64;
    for (int hg = 0; hg < 16; ++hg) {
      const int hl = hb + hg * 4;
      const int h  = h0 + hl;
      const float4 wv0 = ntload4(wp + (size_t)(h + 0) * (kD / 4) + lane);
      const float4 wv1 = ntload4(wp + (size_t)(h + 1) * (kD / 4) + lane);
      const float4 wv2 = ntload4(wp + (size_t)(h + 2) * (kD / 4) + lane);
      const float4 wv3 = ntload4(wp + (size_t)(h + 3) * (kD / 4) + lane);
#pragma unroll
      for (int b = 0; b < kB; ++b) {
        const float4 hv = *reinterpret_cast<const float4*>(&hid[b][hl]);
        acc2[b].x = fmaf(hv.x, wv0.x, acc2[b].x);
        acc2[b].y = fmaf(hv.x, wv0.y, acc2[b].y);
        acc2[b].z = fmaf(hv.x, wv0.z, acc2[b].z);
        acc2[b].w = fmaf(hv.x, wv0.w, acc2[b].w);
        acc2[b].x = fmaf(hv.y, wv1.x, acc2[b].x);
        acc2[b].y = fmaf(hv.y, wv1.y, acc2[b].y);
        acc2[b].z = fmaf(hv.y, wv1.z, acc2[b].z);
        acc2[b].w = fmaf(hv.y, wv1.w, acc2[b].w);
        acc2[b].x = fmaf(hv.z, wv2.x, acc2[b].x);
        acc2[b].y = fmaf(hv.z, wv2.y, acc2[b].y);
        acc2[b].z = fmaf(hv.z, wv2.z, acc2[b].z);
        acc2[b].w = fmaf(hv.z, wv2.w, acc2[b].w);
        acc2[b].x = fmaf(hv.w, wv3.x, acc2[b].x);
        acc2[b].y = fmaf(hv.w, wv3.y, acc2[b].y);
        acc2[b].z = fmaf(hv.w, wv3.z, acc2[b].z);
        acc2[b].w = fmaf(hv.w, wv3.w, acc2[b].w);
      }
    }
  }
  // cross-wave combine into red by rotation
#pragma unroll
  for (int g = 0; g < 4; ++g) {
    if (wave == g) {
#pragma unroll
      for (int b = 0; b < kB; ++b) {
        float4* rp = reinterpret_cast<float4*>(&red[b][0]) + lane;
        if (g == 0) {
          *rp = acc2[b];
        } else {
          float4 v = *rp;
          v.x += acc2[b].x; v.y += acc2[b].y; v.z += acc2[b].z; v.w += acc2[b].w;
          *rp = v;
        }
      }
    }
    __syncthreads();
  }

  // ---- epilogue: thread owns d = tid; gate-scale and accumulate over e ----
  {
    const float b2v = (c == 0) ? b2[(size_t)te * kD + tid] : 0.f;
#pragma unroll
    for (int b = 0; b < kB; ++b)
      atomicAdd(&out[((size_t)b * kT + t) * kD + tid], gates_s[b] * (red[b][tid] + b2v));

    if (c == 0 && tid == 0) {
      float gs = 0.f;
#pragma unroll
      for (int b = 0; b < kB; ++b) gs += gates_s[b];
      atomicAdd(&out[(size_t)kB * kT * kD], 0.01f * gs * (1.0f / (kB * kT)));
    }
  }
}

}  // namespace

extern "C" void kernel_launch(void* const* d_in, const int* in_sizes, int n_in,
                              void* d_out, int out_size, void* d_ws, size_t ws_size,
                              hipStream_t stream) {
  const float* x   = (const float*)d_in[0];
  const float* fc1 = (const float*)d_in[1];
  const float* b1  = (const float*)d_in[2];
  const float* fc2 = (const float*)d_in[3];
  const float* b2  = (const float*)d_in[4];
  const float* Wr  = (const float*)d_in[5];
  const float* br  = (const float*)d_in[6];
  float* out = (float*)d_out;

  // Zero the accumulation target every call (graph replays must be
  // deterministic; harness does not re-poison between replays).
  (void)hipMemsetAsync(d_out, 0, (size_t)out_size * sizeof(float), stream);

  moe_ffn_kernel<<<dim3(kT * kE * kNC), dim3(256), 0, stream>>>(
      x, fc1, b1, fc2, b2, Wr, br, out);
}